// Round 15
// baseline (190.950 us; speedup 1.0000x reference)
//
#include <hip/hip_runtime.h>

typedef unsigned short ushort_t;
typedef unsigned int uint32;
typedef __attribute__((ext_vector_type(8))) short short8;
typedef __attribute__((ext_vector_type(4))) float f32x4;

static __device__ __forceinline__ ushort_t f2bf(float f) {
  uint32 u = __builtin_bit_cast(uint32, f);
  u += 0x7fffu + ((u >> 16) & 1u);   // round-to-nearest-even
  return (ushort_t)(u >> 16);
}
static __device__ __forceinline__ float bf2f(ushort_t h) {
  return __builtin_bit_cast(float, (uint32)h << 16);
}

static __device__ __forceinline__ void gload_lds16(const ushort_t* g, ushort_t* l) {
  __builtin_amdgcn_global_load_lds(
      (const __attribute__((address_space(1))) uint32*)g,
      (__attribute__((address_space(3))) uint32*)l, 16, 0, 0);
}

static __device__ __forceinline__ ushort4 cvt4(float4 v) {
  ushort4 u;
  u.x = f2bf(v.x); u.y = f2bf(v.y); u.z = f2bf(v.z); u.w = f2bf(v.w);
  return u;
}
static __device__ __forceinline__ ushort4 cvt4s(float4 a, float4 b) {
  ushort4 u;
  u.x = f2bf(a.x + b.x); u.y = f2bf(a.y + b.y);
  u.z = f2bf(a.z + b.z); u.w = f2bf(a.w + b.w);
  return u;
}

// ---------------------------------------------------------------------------
// ctx block (device func): partial ctx tiles, NO atomics, bf16 LDS staging.
// cb in [0,256): branch-3 -> ctxP[(bh*4+chunk)*4096]; [256,320): branch-4 ->
// ctxP[1048576 + bh*4096]. sm must hold >= 8704 ushorts.
// ---------------------------------------------------------------------------
static __device__ __forceinline__ void ctx_block(
    const ushort_t* __restrict__ ks3, const ushort_t* __restrict__ v3,
    const ushort_t* __restrict__ ks4, const ushort_t* __restrict__ v4,
    float* __restrict__ ctxP, int cb, ushort_t* sm) {
  ushort_t (*ks_s)[68] = reinterpret_cast<ushort_t(*)[68]>(sm);
  ushort_t (*v_s)[68] = reinterpret_cast<ushort_t(*)[68]>(sm + 4352);
  const int t = threadIdx.x;
  const ushort_t* ks; const ushort_t* v; float* dst; int Nk, bh, chunk;
  if (cb < 256) {
    bh = cb >> 2; chunk = cb & 3;
    ks = ks3; v = v3; Nk = 1024;
    dst = ctxP + (size_t)((bh << 2) + chunk) * 4096;
  } else {
    bh = cb - 256; chunk = 0;
    ks = ks4; v = v4; Nk = 256;
    dst = ctxP + 1048576 + (size_t)bh * 4096;
  }
  const int bb = bh >> 3, h = bh & 7;
  const int td = t & 15, te = t >> 4;
  float acc[4][4] = {};
  size_t rowBase = (size_t)bb * Nk + chunk * 256;
  for (int n0 = 0; n0 < 256; n0 += 64) {
#pragma unroll
    for (int i = 0; i < 4; i++) {
      int idx = i * 256 + t;            // 0..1023 = 64 n x 16 quads
      int n = idx >> 4, dq = idx & 15;
      size_t g = (rowBase + n0 + n) * 512 + h * 64 + dq * 4;
      *reinterpret_cast<ushort4*>(&ks_s[n][dq * 4]) = *reinterpret_cast<const ushort4*>(ks + g);
      *reinterpret_cast<ushort4*>(&v_s[n][dq * 4]) = *reinterpret_cast<const ushort4*>(v + g);
    }
    __syncthreads();
#pragma unroll 8
    for (int n = 0; n < 64; n++) {
      ushort4 cu = *reinterpret_cast<const ushort4*>(&ks_s[n][td * 4]);
      ushort4 vu = *reinterpret_cast<const ushort4*>(&v_s[n][te * 4]);
      float ca[4] = {bf2f(cu.x), bf2f(cu.y), bf2f(cu.z), bf2f(cu.w)};
      float va[4] = {bf2f(vu.x), bf2f(vu.y), bf2f(vu.z), bf2f(vu.w)};
#pragma unroll
      for (int i = 0; i < 4; i++)
#pragma unroll
        for (int j = 0; j < 4; j++) acc[i][j] += ca[i] * va[j];
    }
    __syncthreads();
  }
#pragma unroll
  for (int i = 0; i < 4; i++) {
    float4 o = make_float4(acc[i][0], acc[i][1], acc[i][2], acc[i][3]);
    *reinterpret_cast<float4*>(&dst[(td * 4 + i) * 64 + te * 4]) = o;
  }
}

// ---------------------------------------------------------------------------
// prepA (runs FIRST): [big-ws] blocks 0..2047 stream f2p = bf16(f2+f2pe);
// then kv inputs + weights fp32->bf16 + bqc + Z=0. No LDS, no launch bounds
// -> max occupancy for the streams. grid = streamBlocks + 3329.
// ---------------------------------------------------------------------------
__global__ void prepA_kernel(const float* __restrict__ f2, const float* __restrict__ f2pe,
                             ushort_t* __restrict__ f2p,
                             const float* __restrict__ f3, const float* __restrict__ f3pe,
                             const float* __restrict__ f4, const float* __restrict__ f4pe,
                             const float* __restrict__ Wq1, const float* __restrict__ Wq2,
                             const float* __restrict__ Wk1, const float* __restrict__ Wv1,
                             const float* __restrict__ Wk2, const float* __restrict__ Wv2,
                             const float* __restrict__ bq1, const float* __restrict__ bq2,
                             ushort_t* __restrict__ f3p, ushort_t* __restrict__ f3b,
                             ushort_t* __restrict__ f4p, ushort_t* __restrict__ f4b,
                             ushort_t* __restrict__ WqB, ushort_t* __restrict__ Wk1B,
                             ushort_t* __restrict__ Wv1B, ushort_t* __restrict__ Wk2B,
                             ushort_t* __restrict__ Wv2B, float* __restrict__ bqc,
                             float* __restrict__ Z, int streamBlocks) {
  int b0 = blockIdx.x, t = threadIdx.x;
  if (b0 < streamBlocks) {
    // f2p stream: 2048 float4 per block, 8 loads in flight
    const int base = b0 * 2048;
    const float4* A4 = reinterpret_cast<const float4*>(f2);
    const float4* P4 = reinterpret_cast<const float4*>(f2pe);
#pragma unroll
    for (int half = 0; half < 2; half++) {
      float4 a[4], p[4];
#pragma unroll
      for (int j = 0; j < 4; j++) {
        int i = base + (half * 4 + j) * 256 + t;
        a[j] = A4[i];
        p[j] = P4[i];
      }
#pragma unroll
      for (int j = 0; j < 4; j++) {
        int i = base + (half * 4 + j) * 256 + t;
        reinterpret_cast<ushort4*>(f2p)[i] = cvt4s(a[j], p[j]);
      }
    }
    return;
  }
  int b = b0 - streamBlocks;
  if (b < 2048) {
    int i0 = b * 512 + t, i1 = i0 + 256;
    const float4* A4 = reinterpret_cast<const float4*>(f3);
    const float4* P4 = reinterpret_cast<const float4*>(f3pe);
    float4 a0 = A4[i0], a1 = A4[i1], p0 = P4[i0], p1 = P4[i1];
    reinterpret_cast<ushort4*>(f3b)[i0] = cvt4(a0);
    reinterpret_cast<ushort4*>(f3b)[i1] = cvt4(a1);
    reinterpret_cast<ushort4*>(f3p)[i0] = cvt4s(a0, p0);
    reinterpret_cast<ushort4*>(f3p)[i1] = cvt4s(a1, p1);
  } else if (b < 2560) {
    int i0 = (b - 2048) * 512 + t, i1 = i0 + 256;
    const float4* A4 = reinterpret_cast<const float4*>(f4);
    const float4* P4 = reinterpret_cast<const float4*>(f4pe);
    float4 a0 = A4[i0], a1 = A4[i1], p0 = P4[i0], p1 = P4[i1];
    reinterpret_cast<ushort4*>(f4b)[i0] = cvt4(a0);
    reinterpret_cast<ushort4*>(f4b)[i1] = cvt4(a1);
    reinterpret_cast<ushort4*>(f4p)[i0] = cvt4s(a0, p0);
    reinterpret_cast<ushort4*>(f4p)[i1] = cvt4s(a1, p1);
  } else if (b < 3328) {
    int u = b - 2560;
    int arr = u >> 7, i0 = (u & 127) * 512 + t, i1 = i0 + 256;
    const float* s; ushort_t* d;
    switch (arr) {
      case 0: s = Wq1; d = WqB; break;
      case 1: s = Wq2; d = WqB + 262144; break;
      case 2: s = Wk1; d = Wk1B; break;
      case 3: s = Wv1; d = Wv1B; break;
      case 4: s = Wk2; d = Wk2B; break;
      default: s = Wv2; d = Wv2B; break;
    }
    const float4* S4 = reinterpret_cast<const float4*>(s);
    float4 v0 = S4[i0], v1 = S4[i1];
    reinterpret_cast<ushort4*>(d)[i0] = cvt4(v0);
    reinterpret_cast<ushort4*>(d)[i1] = cvt4(v1);
  } else {
    for (int i = t; i < 512; i += 256) { bqc[i] = bq1[i]; bqc[512 + i] = bq2[i]; }
    for (int i = t; i < 8192; i += 256) Z[i] = 0.f;
  }
}

// ---------------------------------------------------------------------------
// Shared GEMM core: 128x128 tile, 4 waves, BK=64, global_load_lds staging.
// LDS: row-major 128 x 128B, XOR-swizzle byte ^= ((row&7)<<4).
// ---------------------------------------------------------------------------
static __device__ __forceinline__ void gemm_core(
    const ushort_t* __restrict__ A, const ushort_t* __restrict__ Bt,
    int K, int mBase, int nBase, ushort_t* As, ushort_t* Bs, f32x4 acc[4][4]) {
  const int t = threadIdx.x;
  const int w = t >> 6, l = t & 63;
  const int l15 = l & 15, l4 = l >> 4;
  const int rowInSeg = l >> 3;
  const int srcOff = ((l & 7) ^ rowInSeg) << 3;
  const int wm = (w >> 1) * 64, wn = (w & 1) * 64;

  for (int k0 = 0; k0 < K; k0 += 64) {
#pragma unroll
    for (int i = 0; i < 4; i++) {
      int seg = w * 4 + i;
      int row = seg * 8 + rowInSeg;
      gload_lds16(A + (size_t)(mBase + row) * K + k0 + srcOff, As + seg * 512);
      gload_lds16(Bt + (size_t)(nBase + row) * K + k0 + srcOff, Bs + seg * 512);
    }
    __syncthreads();
#pragma unroll
    for (int kk = 0; kk < 2; kk++) {
      short8 af[4], bfr[4];
      const int kb = kk * 64 + l4 * 16;
#pragma unroll
      for (int f = 0; f < 4; f++) {
        int rowA = wm + f * 16 + l15;
        af[f] = *reinterpret_cast<const short8*>(
            reinterpret_cast<const char*>(As) + rowA * 128 + (kb ^ ((rowA & 7) << 4)));
        int rowB = wn + f * 16 + l15;
        bfr[f] = *reinterpret_cast<const short8*>(
            reinterpret_cast<const char*>(Bs) + rowB * 128 + (kb ^ ((rowB & 7) << 4)));
      }
#pragma unroll
      for (int fm = 0; fm < 4; fm++)
#pragma unroll
        for (int fn = 0; fn < 4; fn++)
          acc[fm][fn] = __builtin_amdgcn_mfma_f32_16x16x32_bf16(af[fm], bfr[fn], acc[fm][fn], 0, 0, 0);
    }
    __syncthreads();
  }
}

// ---------------------------------------------------------------------------
// G1: blocks [0,ctxBlocks) run ctx (LEADING — hide in dispatch ramp);
// blocks >= ctxBlocks: E = exp(f2p @ WqB^T + bqc), colsums into Z.
// GEMM grid 2048 = 256 m x 8 n, XCD-chunked swizzle, fn-inner stores.
// ---------------------------------------------------------------------------
__global__ __launch_bounds__(256, 4)
void gemm_g1(const ushort_t* __restrict__ A, const ushort_t* __restrict__ Bt,
             const float* __restrict__ bias, ushort_t* __restrict__ E,
             float* __restrict__ Z,
             const ushort_t* __restrict__ ks3, const ushort_t* __restrict__ v3,
             const ushort_t* __restrict__ ks4, const ushort_t* __restrict__ v4,
             float* __restrict__ ctxP, int ctxBlocks) {
  __shared__ ushort_t smem[16384];
  if ((int)blockIdx.x < ctxBlocks) {
    ctx_block(ks3, v3, ks4, v4, ctxP, blockIdx.x, smem);
    return;
  }
  ushort_t* As = smem;
  ushort_t* Bs = smem + 8192;
  const int bid = blockIdx.x - ctxBlocks;
  const int swz = (bid & 7) * 256 + (bid >> 3);
  const int mBase = (swz >> 3) * 128, nBase = (swz & 7) * 128;
  const int t = threadIdx.x, w = t >> 6, lane = t & 63;
  const int l15 = lane & 15, l4 = lane >> 4;
  const int wm = (w >> 1) * 64, wn = (w & 1) * 64;

  f32x4 acc[4][4];
#pragma unroll
  for (int i = 0; i < 4; i++)
#pragma unroll
    for (int j = 0; j < 4; j++) acc[i][j] = (f32x4){0.f, 0.f, 0.f, 0.f};

  gemm_core(A, Bt, 512, mBase, nBase, As, Bs, acc);

  const int N = 1024;
  float bcol[4], csum[4] = {0.f, 0.f, 0.f, 0.f};
#pragma unroll
  for (int fn = 0; fn < 4; fn++) bcol[fn] = bias[nBase + wn + fn * 16 + l15];
#pragma unroll
  for (int fm = 0; fm < 4; fm++) {
#pragma unroll
    for (int r = 0; r < 4; r++) {
      int row = mBase + wm + fm * 16 + l4 * 4 + r;
      float ex[4];
#pragma unroll
      for (int fn = 0; fn < 4; fn++) {
        ex[fn] = __expf(acc[fm][fn][r] + bcol[fn]);
        csum[fn] += ex[fn];
      }
#pragma unroll
      for (int fn = 0; fn < 4; fn++)
        E[(size_t)row * N + nBase + wn + fn * 16 + l15] = f2bf(ex[fn]);
    }
  }
#pragma unroll
  for (int fn = 0; fn < 4; fn++) {
    float s = csum[fn];
    s += __shfl_xor(s, 16);
    s += __shfl_xor(s, 32);
    if (l4 == 0) atomicAdd(&Z[(mBase >> 12) * 1024 + nBase + wn + fn * 16 + l15], s);
  }
}

// ---------------------------------------------------------------------------
// KV quad: four kv GEMMs (N=512, K=512) with fused k-softmax. grid 640,
// XCD-chunked swizzle.
// ---------------------------------------------------------------------------
__global__ __launch_bounds__(256, 4)
void kv_quad(const ushort_t* __restrict__ f3p, const ushort_t* __restrict__ f3b,
             const ushort_t* __restrict__ f4p, const ushort_t* __restrict__ f4b,
             const ushort_t* __restrict__ Wk1B, const ushort_t* __restrict__ Wv1B,
             const ushort_t* __restrict__ Wk2B, const ushort_t* __restrict__ Wv2B,
             const float* __restrict__ bk1, const float* __restrict__ bv1,
             const float* __restrict__ bk2, const float* __restrict__ bv2,
             ushort_t* __restrict__ ks3, ushort_t* __restrict__ v3,
             ushort_t* __restrict__ ks4, ushort_t* __restrict__ v4) {
  __shared__ ushort_t As[8192], Bs[8192];
  const int bid = blockIdx.x;
  const int id = (bid & 7) * 80 + (bid >> 3);
  const ushort_t* A; const ushort_t* Bt; const float* bias; ushort_t* out;
  bool doSM; int loc;
  if (id < 256)      { A = f3p; Bt = Wk1B; bias = bk1; out = ks3; doSM = true;  loc = id; }
  else if (id < 512) { A = f3b; Bt = Wv1B; bias = bv1; out = v3;  doSM = false; loc = id - 256; }
  else if (id < 576) { A = f4p; Bt = Wk2B; bias = bk2; out = ks4; doSM = true;  loc = id - 512; }
  else               { A = f4b; Bt = Wv2B; bias = bv2; out = v4;  doSM = false; loc = id - 576; }
  const int nBase = (loc & 3) * 128, mBase = (loc >> 2) * 128;
  const int t = threadIdx.x, w = t >> 6, lane = t & 63;
  const int l15 = lane & 15, l4 = lane >> 4;
  const int wm = (w >> 1) * 64, wn = (w & 1) * 64;

  f32x4 acc[4][4];
#pragma unroll
  for (int i = 0; i < 4; i++)
#pragma unroll
    for (int j = 0; j < 4; j++) acc[i][j] = (f32x4){0.f, 0.f, 0.f, 0.f};

  gemm_core(A, Bt, 512, mBase, nBase, As, Bs, acc);

  const int N = 512;
  float bcol[4];
#pragma unroll
  for (int fn = 0; fn < 4; fn++) bcol[fn] = bias[nBase + wn + fn * 16 + l15];

  if (doSM) {
#pragma unroll
    for (int fm = 0; fm < 4; fm++) {
#pragma unroll
      for (int r = 0; r < 4; r++) {
        float x[4], m = -1e30f;
#pragma unroll
        for (int fn = 0; fn < 4; fn++) { x[fn] = acc[fm][fn][r] + bcol[fn]; m = fmaxf(m, x[fn]); }
        m = fmaxf(m, __shfl_xor(m, 1));
        m = fmaxf(m, __shfl_xor(m, 2));
        m = fmaxf(m, __shfl_xor(m, 4));
        m = fmaxf(m, __shfl_xor(m, 8));
        float s = 0.f;
#pragma unroll
        for (int fn = 0; fn < 4; fn++) { x[fn] = __expf(x[fn] - m); s += x[fn]; }
        s += __shfl_xor(s, 1);
        s += __shfl_xor(s, 2);
        s += __shfl_xor(s, 4);
        s += __shfl_xor(s, 8);
        float inv = 1.f / s;
        int row = mBase + wm + fm * 16 + l4 * 4 + r;
#pragma unroll
        for (int fn = 0; fn < 4; fn++)
          out[(size_t)row * N + nBase + wn + fn * 16 + l15] = f2bf(x[fn] * inv);
      }
    }
  } else {
#pragma unroll
    for (int fm = 0; fm < 4; fm++) {
#pragma unroll
      for (int r = 0; r < 4; r++) {
        int row = mBase + wm + fm * 16 + l4 * 4 + r;
#pragma unroll
        for (int fn = 0; fn < 4; fn++)
          out[(size_t)row * N + nBase + wn + fn * 16 + l15] =
              f2bf(acc[fm][fn][r] + bcol[fn]);
      }
    }
  }
}

// ---------------------------------------------------------------------------
// ctx standalone + prepB (fallback path, small ws only)
// ---------------------------------------------------------------------------
__global__ __launch_bounds__(256)
void ctx_kernel(const ushort_t* __restrict__ ks3, const ushort_t* __restrict__ v3,
                const ushort_t* __restrict__ ks4, const ushort_t* __restrict__ v4,
                float* __restrict__ ctxP) {
  __shared__ ushort_t sm[8704];
  ctx_block(ks3, v3, ks4, v4, ctxP, blockIdx.x, sm);
}

__global__ __launch_bounds__(256)
void prepB_kernel(const float* __restrict__ f2, const float* __restrict__ f2pe,
                  ushort_t* __restrict__ f2p) {
  const int base = blockIdx.x * 1024, t = threadIdx.x;
  const float4* A4 = reinterpret_cast<const float4*>(f2);
  const float4* P4 = reinterpret_cast<const float4*>(f2pe);
#pragma unroll
  for (int j = 0; j < 4; j++) {
    int i = base + j * 256 + t;
    float4 a = A4[i], p = P4[i];
    reinterpret_cast<ushort4*>(f2p)[i] = cvt4s(a, p);
  }
}

// ---------------------------------------------------------------------------
// G2: out_fp32 = E @ Mt(batch)^T + br.  grid 1024 = 256 m x 4 n, XCD swizzle.
// ---------------------------------------------------------------------------
__global__ __launch_bounds__(256, 4)
void gemm_g2(const ushort_t* __restrict__ E, const ushort_t* __restrict__ Mt,
             const float* __restrict__ bias, float* __restrict__ C) {
  __shared__ ushort_t As[8192], Bs[8192];
  const int bid = blockIdx.x;
  const int swz = (bid & 7) * 128 + (bid >> 3);
  const int tx = swz & 3, ty = swz >> 2;
  const int mBase = ty * 128, nBase = tx * 128;
  const ushort_t* Btb = Mt + (size_t)(ty >> 5) * 524288;
  const int t = threadIdx.x, w = t >> 6, lane = t & 63;
  const int l15 = lane & 15, l4 = lane >> 4;
  const int wm = (w >> 1) * 64, wn = (w & 1) * 64;

  f32x4 acc[4][4];
#pragma unroll
  for (int i = 0; i < 4; i++)
#pragma unroll
    for (int j = 0; j < 4; j++) acc[i][j] = (f32x4){0.f, 0.f, 0.f, 0.f};

  gemm_core(E, Btb, 1024, mBase, nBase, As, Bs, acc);

  const int N = 512;
  float bcol[4];
#pragma unroll
  for (int fn = 0; fn < 4; fn++) bcol[fn] = bias[nBase + wn + fn * 16 + l15];
#pragma unroll
  for (int fm = 0; fm < 4; fm++) {
#pragma unroll
    for (int r = 0; r < 4; r++) {
      int row = mBase + wm + fm * 16 + l4 * 4 + r;
#pragma unroll
      for (int fn = 0; fn < 4; fn++)
        C[(size_t)row * N + nBase + wn + fn * 16 + l15] = acc[fm][fn][r] + bcol[fn];
    }
  }
}

// ---------------------------------------------------------------------------
// Fold: Mt[b][j][c] = (sum_e ctx[branch,b,h,d,e]*Wr[j, branch*512+h*64+e]) / Z[b,c]
// branch-3 ctx = sum of 4 partial tiles; branch-4 single tile.
// ---------------------------------------------------------------------------
__global__ __launch_bounds__(256)
void fold_kernel(const float* __restrict__ ctxP, const float* __restrict__ Wr,
                 const float* __restrict__ Z, ushort_t* __restrict__ Mt) {
  __shared__ float ctxT[64][68];   // [e][d]
  __shared__ float wrT[64][68];    // [e][jl]
  __shared__ float zinv[64];
  int blk = blockIdx.x;
  int jc = blk & 7;
  int h = (blk >> 3) & 7;
  int branch = (blk >> 6) & 1;
  int b = blk >> 7;
  int t = threadIdx.x;
  int cbase = branch * 512 + h * 64;
  if (branch == 0) {
    const float* p = ctxP + (size_t)((b * 8 + h) * 4) * 4096;
#pragma unroll
    for (int i = 0; i < 16; i++) {
      int idx = i * 256 + t;
      int d = idx >> 6, e = idx & 63;
      int o = d * 64 + e;
      ctxT[e][d] = p[o] + p[4096 + o] + p[8192 + o] + p[12288 + o];
    }
  } else {
    const float* p = ctxP + 1048576 + (size_t)(b * 8 + h) * 4096;
#pragma unroll
    for (int i = 0; i < 16; i++) {
      int idx = i * 256 + t;
      int d = idx >> 6, e = idx & 63;
      ctxT[e][d] = p[d * 64 + e];
    }
  }
#pragma unroll
  for (int i = 0; i < 16; i++) {
    int idx = i * 256 + t;
    int jl = idx >> 6, e = idx & 63;
    wrT[e][jl] = Wr[(size_t)(jc * 64 + jl) * 1024 + cbase + e];
  }
  if (t < 64) zinv[t] = 1.0f / Z[b * 1024 + cbase + t];
  __syncthreads();
  int td = t & 15, tj = t >> 4;
  float acc[4][4] = {};   // [d_i][jj]
#pragma unroll 8
  for (int e = 0; e < 64; e++) {
    float4 cv = *reinterpret_cast<const float4*>(&ctxT[e][td * 4]);
    float4 wv = *reinterpret_cast<const float4*>(&wrT[e][tj * 4]);
    float ca[4] = {cv.x, cv.y, cv.z, cv.w};
    float wa[4] = {wv.x, wv.y, wv.z, wv.w};
#pragma unroll
    for (int i = 0; i < 4; i++)
#pragma unroll
      for (int jj = 0; jj < 4; jj++) acc[i][jj] += ca[i] * wa[jj];
  }
  float zi[4] = {zinv[td * 4], zinv[td * 4 + 1], zinv[td * 4 + 2], zinv[td * 4 + 3]};
#pragma unroll
  for (int jj = 0; jj < 4; jj++) {
    ushort4 u;
    u.x = f2bf(acc[0][jj] * zi[0]);
    u.y = f2bf(acc[1][jj] * zi[1]);
    u.z = f2bf(acc[2][jj] * zi[2]);
    u.w = f2bf(acc[3][jj] * zi[3]);
    *reinterpret_cast<ushort4*>(
        &Mt[(size_t)(b * 512 + jc * 64 + tj * 4 + jj) * 1024 + cbase + td * 4]) = u;
  }
}

// ---------------------------------------------------------------------------
extern "C" void kernel_launch(void* const* d_in, const int* in_sizes, int n_in,
                              void* d_out, int out_size, void* d_ws, size_t ws_size,
                              hipStream_t stream) {
  const float* f2 = (const float*)d_in[0];
  const float* f3 = (const float*)d_in[1];
  const float* f4 = (const float*)d_in[2];
  const float* f2pe = (const float*)d_in[3];
  const float* f3pe = (const float*)d_in[4];
  const float* f4pe = (const float*)d_in[5];
  const float* Wq1 = (const float*)d_in[6];
  const float* bq1 = (const float*)d_in[7];
  const float* Wk1 = (const float*)d_in[8];
  const float* bk1 = (const float*)d_in[9];
  const float* Wv1 = (const float*)d_in[10];
  const float* bv1 = (const float*)d_in[11];
  const float* Wq2 = (const float*)d_in[12];
  const float* bq2 = (const float*)d_in[13];
  const float* Wk2 = (const float*)d_in[14];
  const float* bk2 = (const float*)d_in[15];
  const float* Wv2 = (const float*)d_in[16];
  const float* bv2 = (const float*)d_in[17];
  const float* Wr = (const float*)d_in[18];
  const float* br = (const float*)d_in[19];

  char* ws = (char*)d_ws;
  // Region 0: E bf16 [32768,1024]
  ushort_t* E = (ushort_t*)(ws + 0);                       // 67,108,864 B
  // Region 1 (33.5 MB): kv inputs; small-ws path reuses it for f2p after kvq
  char* R1 = ws + 67108864;
  ushort_t* f3p = (ushort_t*)R1;                           // 8,388,608
  ushort_t* f3b = (ushort_t*)(R1 + 8388608);               // 8,388,608
  ushort_t* f4p = (ushort_t*)(R1 + 16777216);              // 2,097,152
  ushort_t* f4b = (ushort_t*)(R1 + 18874368);              // 2,097,152
  // Region 2: kv GEMM outputs (softmaxed k + v, bf16)
  char* R2 = ws + 100663296;
  ushort_t* ks3 = (ushort_t*)R2;
  ushort_t* v3b = (ushort_t*)(R2 + 8388608);
  ushort_t* ks4 = (ushort_t*)(R2 + 16777216);
  ushort_t* v4b = (ushort_t*)(R2 + 18874368);
  // Region 3: weights bf16, Mt, Z, bqc, ctx partials (5 MB)
  char* R3 = ws + 121634816;
  ushort_t* WqB = (ushort_t*)R3;                           // 1,048,576
  ushort_t* Wk1B = (ushort_t*)(R3 + 1048576);
  ushort_t* Wv1B = (ushort_t*)(R3 + 1572864);
  ushort_t* Wk2B = (ushort_t*)(R3 + 2097152);
  ushort_t* Wv2B = (ushort_t*)(R3 + 2621440);
  ushort_t* Mt = (ushort_t*)(R3 + 3145728);                // 8,388,608
  float* Z = (float*)(R3 + 11534336);                      // 32,768
  float* bqc = (float*)(R3 + 11567104);                    // 4,096
  float* ctxP = (float*)(R3 + 11571200);                   // 5,242,880
  // Region 4 (big-ws only): dedicated f2p, disjoint from all live buffers
  const bool bigWS = ws_size >= (size_t)176160768;         // needs 168 MiB
  ushort_t* f2p = bigWS ? (ushort_t*)(ws + 142606336) : (ushort_t*)R1;

  if (bigWS) {
    // prepA: f2p stream (2048 blocks, max-occupancy) + kv inputs + weights
    prepA_kernel<<<5377, 256, 0, stream>>>(f2, f2pe, f2p, f3, f3pe, f4, f4pe,
                                           Wq1, Wq2, Wk1, Wv1, Wk2, Wv2, bq1, bq2,
                                           f3p, f3b, f4p, f4b,
                                           WqB, Wk1B, Wv1B, Wk2B, Wv2B, bqc, Z, 2048);
    // kv GEMMs (pure, 640 blocks)
    kv_quad<<<640, 256, 0, stream>>>(f3p, f3b, f4p, f4b,
                                     Wk1B, Wv1B, Wk2B, Wv2B,
                                     bk1, bv1, bk2, bv2,
                                     ks3, v3b, ks4, v4b);
    // G1 GEMM (2048) + LEADING ctx (320) — ctx hides in the dispatch ramp
    gemm_g1<<<2368, 256, 0, stream>>>(f2p, WqB, bqc, E, Z,
                                      ks3, v3b, ks4, v4b, ctxP, 320);
  } else {
    prepA_kernel<<<3329, 256, 0, stream>>>(f2, f2pe, f2p, f3, f3pe, f4, f4pe,
                                           Wq1, Wq2, Wk1, Wv1, Wk2, Wv2, bq1, bq2,
                                           f3p, f3b, f4p, f4b,
                                           WqB, Wk1B, Wv1B, Wk2B, Wv2B, bqc, Z, 0);
    kv_quad<<<640, 256, 0, stream>>>(f3p, f3b, f4p, f4b,
                                     Wk1B, Wv1B, Wk2B, Wv2B,
                                     bk1, bv1, bk2, bv2,
                                     ks3, v3b, ks4, v4b);
    prepB_kernel<<<4096, 256, 0, stream>>>(f2, f2pe, f2p);
    ctx_kernel<<<320, 256, 0, stream>>>(ks3, v3b, ks4, v4b, ctxP);
    gemm_g1<<<2048, 256, 0, stream>>>(f2p, WqB, bqc, E, Z,
                                      ks3, v3b, ks4, v4b, ctxP, 0);
  }

  // ---- fold ctx partials, Wr, 1/Z into per-batch Mt[b][j][c] ----
  fold_kernel<<<1024, 256, 0, stream>>>(ctxP, Wr, Z, Mt);

  // ---- G2: out = E @ Mt^T + br (E L3-hot from G1) ----
  gemm_g2<<<1024, 256, 0, stream>>>(E, Mt, br, (float*)d_out);
}

// Round 16
// 172.974 us; speedup vs baseline: 1.1039x; 1.1039x over previous
//
#include <hip/hip_runtime.h>

typedef unsigned short ushort_t;
typedef unsigned int uint32;
typedef __attribute__((ext_vector_type(8))) short short8;
typedef __attribute__((ext_vector_type(4))) float f32x4;

static __device__ __forceinline__ ushort_t f2bf(float f) {
  uint32 u = __builtin_bit_cast(uint32, f);
  u += 0x7fffu + ((u >> 16) & 1u);   // round-to-nearest-even
  return (ushort_t)(u >> 16);
}
static __device__ __forceinline__ float bf2f(ushort_t h) {
  return __builtin_bit_cast(float, (uint32)h << 16);
}

static __device__ __forceinline__ void gload_lds16(const ushort_t* g, ushort_t* l) {
  __builtin_amdgcn_global_load_lds(
      (const __attribute__((address_space(1))) uint32*)g,
      (__attribute__((address_space(3))) uint32*)l, 16, 0, 0);
}

static __device__ __forceinline__ ushort4 cvt4(float4 v) {
  ushort4 u;
  u.x = f2bf(v.x); u.y = f2bf(v.y); u.z = f2bf(v.z); u.w = f2bf(v.w);
  return u;
}
static __device__ __forceinline__ ushort4 cvt4s(float4 a, float4 b) {
  ushort4 u;
  u.x = f2bf(a.x + b.x); u.y = f2bf(a.y + b.y);
  u.z = f2bf(a.z + b.z); u.w = f2bf(a.w + b.w);
  return u;
}

// ---------------------------------------------------------------------------
// ctx block (device func): partial ctx tiles, NO atomics, bf16 LDS staging.
// cb in [0,256): branch-3 -> ctxP[(bh*4+chunk)*4096]; [256,320): branch-4 ->
// ctxP[1048576 + bh*4096]. sm must hold >= 8704 ushorts.
// ---------------------------------------------------------------------------
static __device__ __forceinline__ void ctx_block(
    const ushort_t* __restrict__ ks3, const ushort_t* __restrict__ v3,
    const ushort_t* __restrict__ ks4, const ushort_t* __restrict__ v4,
    float* __restrict__ ctxP, int cb, ushort_t* sm) {
  ushort_t (*ks_s)[68] = reinterpret_cast<ushort_t(*)[68]>(sm);
  ushort_t (*v_s)[68] = reinterpret_cast<ushort_t(*)[68]>(sm + 4352);
  const int t = threadIdx.x;
  const ushort_t* ks; const ushort_t* v; float* dst; int Nk, bh, chunk;
  if (cb < 256) {
    bh = cb >> 2; chunk = cb & 3;
    ks = ks3; v = v3; Nk = 1024;
    dst = ctxP + (size_t)((bh << 2) + chunk) * 4096;
  } else {
    bh = cb - 256; chunk = 0;
    ks = ks4; v = v4; Nk = 256;
    dst = ctxP + 1048576 + (size_t)bh * 4096;
  }
  const int bb = bh >> 3, h = bh & 7;
  const int td = t & 15, te = t >> 4;
  float acc[4][4] = {};
  size_t rowBase = (size_t)bb * Nk + chunk * 256;
  for (int n0 = 0; n0 < 256; n0 += 64) {
#pragma unroll
    for (int i = 0; i < 4; i++) {
      int idx = i * 256 + t;            // 0..1023 = 64 n x 16 quads
      int n = idx >> 4, dq = idx & 15;
      size_t g = (rowBase + n0 + n) * 512 + h * 64 + dq * 4;
      *reinterpret_cast<ushort4*>(&ks_s[n][dq * 4]) = *reinterpret_cast<const ushort4*>(ks + g);
      *reinterpret_cast<ushort4*>(&v_s[n][dq * 4]) = *reinterpret_cast<const ushort4*>(v + g);
    }
    __syncthreads();
#pragma unroll 8
    for (int n = 0; n < 64; n++) {
      ushort4 cu = *reinterpret_cast<const ushort4*>(&ks_s[n][td * 4]);
      ushort4 vu = *reinterpret_cast<const ushort4*>(&v_s[n][te * 4]);
      float ca[4] = {bf2f(cu.x), bf2f(cu.y), bf2f(cu.z), bf2f(cu.w)};
      float va[4] = {bf2f(vu.x), bf2f(vu.y), bf2f(vu.z), bf2f(vu.w)};
#pragma unroll
      for (int i = 0; i < 4; i++)
#pragma unroll
        for (int j = 0; j < 4; j++) acc[i][j] += ca[i] * va[j];
    }
    __syncthreads();
  }
#pragma unroll
  for (int i = 0; i < 4; i++) {
    float4 o = make_float4(acc[i][0], acc[i][1], acc[i][2], acc[i][3]);
    *reinterpret_cast<float4*>(&dst[(td * 4 + i) * 64 + te * 4]) = o;
  }
}

// ---------------------------------------------------------------------------
// prepA (runs FIRST): kv inputs + weights fp32->bf16 + bqc + Z=0.
// 2 iterations/thread, batched loads for ILP. grid = 3329.
// ---------------------------------------------------------------------------
__global__ void prepA_kernel(const float* __restrict__ f3, const float* __restrict__ f3pe,
                             const float* __restrict__ f4, const float* __restrict__ f4pe,
                             const float* __restrict__ Wq1, const float* __restrict__ Wq2,
                             const float* __restrict__ Wk1, const float* __restrict__ Wv1,
                             const float* __restrict__ Wk2, const float* __restrict__ Wv2,
                             const float* __restrict__ bq1, const float* __restrict__ bq2,
                             ushort_t* __restrict__ f3p, ushort_t* __restrict__ f3b,
                             ushort_t* __restrict__ f4p, ushort_t* __restrict__ f4b,
                             ushort_t* __restrict__ WqB, ushort_t* __restrict__ Wk1B,
                             ushort_t* __restrict__ Wv1B, ushort_t* __restrict__ Wk2B,
                             ushort_t* __restrict__ Wv2B, float* __restrict__ bqc,
                             float* __restrict__ Z) {
  int b = blockIdx.x, t = threadIdx.x;
  if (b < 2048) {
    int i0 = b * 512 + t, i1 = i0 + 256;
    const float4* A4 = reinterpret_cast<const float4*>(f3);
    const float4* P4 = reinterpret_cast<const float4*>(f3pe);
    float4 a0 = A4[i0], a1 = A4[i1], p0 = P4[i0], p1 = P4[i1];
    reinterpret_cast<ushort4*>(f3b)[i0] = cvt4(a0);
    reinterpret_cast<ushort4*>(f3b)[i1] = cvt4(a1);
    reinterpret_cast<ushort4*>(f3p)[i0] = cvt4s(a0, p0);
    reinterpret_cast<ushort4*>(f3p)[i1] = cvt4s(a1, p1);
  } else if (b < 2560) {
    int i0 = (b - 2048) * 512 + t, i1 = i0 + 256;
    const float4* A4 = reinterpret_cast<const float4*>(f4);
    const float4* P4 = reinterpret_cast<const float4*>(f4pe);
    float4 a0 = A4[i0], a1 = A4[i1], p0 = P4[i0], p1 = P4[i1];
    reinterpret_cast<ushort4*>(f4b)[i0] = cvt4(a0);
    reinterpret_cast<ushort4*>(f4b)[i1] = cvt4(a1);
    reinterpret_cast<ushort4*>(f4p)[i0] = cvt4s(a0, p0);
    reinterpret_cast<ushort4*>(f4p)[i1] = cvt4s(a1, p1);
  } else if (b < 3328) {
    int u = b - 2560;
    int arr = u >> 7, i0 = (u & 127) * 512 + t, i1 = i0 + 256;
    const float* s; ushort_t* d;
    switch (arr) {
      case 0: s = Wq1; d = WqB; break;
      case 1: s = Wq2; d = WqB + 262144; break;
      case 2: s = Wk1; d = Wk1B; break;
      case 3: s = Wv1; d = Wv1B; break;
      case 4: s = Wk2; d = Wk2B; break;
      default: s = Wv2; d = Wv2B; break;
    }
    const float4* S4 = reinterpret_cast<const float4*>(s);
    float4 v0 = S4[i0], v1 = S4[i1];
    reinterpret_cast<ushort4*>(d)[i0] = cvt4(v0);
    reinterpret_cast<ushort4*>(d)[i1] = cvt4(v1);
  } else {
    for (int i = t; i < 512; i += 256) { bqc[i] = bq1[i]; bqc[512 + i] = bq2[i]; }
    for (int i = t; i < 8192; i += 256) Z[i] = 0.f;
  }
}

// ---------------------------------------------------------------------------
// Shared GEMM core: 128x128 tile, 4 waves, BK=64, global_load_lds staging.
// LDS: row-major 128 x 128B, XOR-swizzle byte ^= ((row&7)<<4).
// ---------------------------------------------------------------------------
static __device__ __forceinline__ void gemm_core(
    const ushort_t* __restrict__ A, const ushort_t* __restrict__ Bt,
    int K, int mBase, int nBase, ushort_t* As, ushort_t* Bs, f32x4 acc[4][4]) {
  const int t = threadIdx.x;
  const int w = t >> 6, l = t & 63;
  const int l15 = l & 15, l4 = l >> 4;
  const int rowInSeg = l >> 3;
  const int srcOff = ((l & 7) ^ rowInSeg) << 3;
  const int wm = (w >> 1) * 64, wn = (w & 1) * 64;

  for (int k0 = 0; k0 < K; k0 += 64) {
#pragma unroll
    for (int i = 0; i < 4; i++) {
      int seg = w * 4 + i;
      int row = seg * 8 + rowInSeg;
      gload_lds16(A + (size_t)(mBase + row) * K + k0 + srcOff, As + seg * 512);
      gload_lds16(Bt + (size_t)(nBase + row) * K + k0 + srcOff, Bs + seg * 512);
    }
    __syncthreads();
#pragma unroll
    for (int kk = 0; kk < 2; kk++) {
      short8 af[4], bfr[4];
      const int kb = kk * 64 + l4 * 16;
#pragma unroll
      for (int f = 0; f < 4; f++) {
        int rowA = wm + f * 16 + l15;
        af[f] = *reinterpret_cast<const short8*>(
            reinterpret_cast<const char*>(As) + rowA * 128 + (kb ^ ((rowA & 7) << 4)));
        int rowB = wn + f * 16 + l15;
        bfr[f] = *reinterpret_cast<const short8*>(
            reinterpret_cast<const char*>(Bs) + rowB * 128 + (kb ^ ((rowB & 7) << 4)));
      }
#pragma unroll
      for (int fm = 0; fm < 4; fm++)
#pragma unroll
        for (int fn = 0; fn < 4; fn++)
          acc[fm][fn] = __builtin_amdgcn_mfma_f32_16x16x32_bf16(af[fm], bfr[fn], acc[fm][fn], 0, 0, 0);
    }
    __syncthreads();
  }
}

// ---------------------------------------------------------------------------
// G1: blocks [0,ctxBlocks) run ctx (LEADING — hide in dispatch ramp);
// blocks >= ctxBlocks: E = exp(f2p @ WqB^T + bqc), colsums into Z.
// GEMM grid 2048 = 256 m x 8 n, XCD-chunked swizzle, fn-inner stores.
// ---------------------------------------------------------------------------
__global__ __launch_bounds__(256, 4)
void gemm_g1(const ushort_t* __restrict__ A, const ushort_t* __restrict__ Bt,
             const float* __restrict__ bias, ushort_t* __restrict__ E,
             float* __restrict__ Z,
             const ushort_t* __restrict__ ks3, const ushort_t* __restrict__ v3,
             const ushort_t* __restrict__ ks4, const ushort_t* __restrict__ v4,
             float* __restrict__ ctxP, int ctxBlocks) {
  __shared__ ushort_t smem[16384];
  if ((int)blockIdx.x < ctxBlocks) {
    ctx_block(ks3, v3, ks4, v4, ctxP, blockIdx.x, smem);
    return;
  }
  ushort_t* As = smem;
  ushort_t* Bs = smem + 8192;
  const int bid = blockIdx.x - ctxBlocks;
  const int swz = (bid & 7) * 256 + (bid >> 3);
  const int mBase = (swz >> 3) * 128, nBase = (swz & 7) * 128;
  const int t = threadIdx.x, w = t >> 6, lane = t & 63;
  const int l15 = lane & 15, l4 = lane >> 4;
  const int wm = (w >> 1) * 64, wn = (w & 1) * 64;

  f32x4 acc[4][4];
#pragma unroll
  for (int i = 0; i < 4; i++)
#pragma unroll
    for (int j = 0; j < 4; j++) acc[i][j] = (f32x4){0.f, 0.f, 0.f, 0.f};

  gemm_core(A, Bt, 512, mBase, nBase, As, Bs, acc);

  const int N = 1024;
  float bcol[4], csum[4] = {0.f, 0.f, 0.f, 0.f};
#pragma unroll
  for (int fn = 0; fn < 4; fn++) bcol[fn] = bias[nBase + wn + fn * 16 + l15];
#pragma unroll
  for (int fm = 0; fm < 4; fm++) {
#pragma unroll
    for (int r = 0; r < 4; r++) {
      int row = mBase + wm + fm * 16 + l4 * 4 + r;
      float ex[4];
#pragma unroll
      for (int fn = 0; fn < 4; fn++) {
        ex[fn] = __expf(acc[fm][fn][r] + bcol[fn]);
        csum[fn] += ex[fn];
      }
#pragma unroll
      for (int fn = 0; fn < 4; fn++)
        E[(size_t)row * N + nBase + wn + fn * 16 + l15] = f2bf(ex[fn]);
    }
  }
#pragma unroll
  for (int fn = 0; fn < 4; fn++) {
    float s = csum[fn];
    s += __shfl_xor(s, 16);
    s += __shfl_xor(s, 32);
    if (l4 == 0) atomicAdd(&Z[(mBase >> 12) * 1024 + nBase + wn + fn * 16 + l15], s);
  }
}

// ---------------------------------------------------------------------------
// KV quad (+ fused f2p stream), SEQUENTIAL dispatch (measured best):
// blocks [0,640) = four kv GEMMs (N=512, K=512) with fused k-softmax;
// blocks >= 640 stream f2p = bf16(f2+f2pe), 2048 float4/block.
// ---------------------------------------------------------------------------
__global__ __launch_bounds__(256, 4)
void kv_quad(const ushort_t* __restrict__ f3p, const ushort_t* __restrict__ f3b,
             const ushort_t* __restrict__ f4p, const ushort_t* __restrict__ f4b,
             const ushort_t* __restrict__ Wk1B, const ushort_t* __restrict__ Wv1B,
             const ushort_t* __restrict__ Wk2B, const ushort_t* __restrict__ Wv2B,
             const float* __restrict__ bk1, const float* __restrict__ bv1,
             const float* __restrict__ bk2, const float* __restrict__ bv2,
             ushort_t* __restrict__ ks3, ushort_t* __restrict__ v3,
             ushort_t* __restrict__ ks4, ushort_t* __restrict__ v4,
             const float* __restrict__ f2, const float* __restrict__ f2pe,
             ushort_t* __restrict__ f2p) {
  __shared__ ushort_t As[8192], Bs[8192];
  const int bid = blockIdx.x;
  if (bid >= 640) {
    const int base = (bid - 640) * 2048;
    const float4* A4 = reinterpret_cast<const float4*>(f2);
    const float4* P4 = reinterpret_cast<const float4*>(f2pe);
    const int t = threadIdx.x;
#pragma unroll
    for (int half = 0; half < 2; half++) {
      float4 a[4], p[4];
#pragma unroll
      for (int j = 0; j < 4; j++) {
        int i = base + (half * 4 + j) * 256 + t;
        a[j] = A4[i];
        p[j] = P4[i];
      }
#pragma unroll
      for (int j = 0; j < 4; j++) {
        int i = base + (half * 4 + j) * 256 + t;
        reinterpret_cast<ushort4*>(f2p)[i] = cvt4s(a[j], p[j]);
      }
    }
    return;
  }
  const int id = (bid & 7) * 80 + (bid >> 3);
  const ushort_t* A; const ushort_t* Bt; const float* bias; ushort_t* out;
  bool doSM; int loc;
  if (id < 256)      { A = f3p; Bt = Wk1B; bias = bk1; out = ks3; doSM = true;  loc = id; }
  else if (id < 512) { A = f3b; Bt = Wv1B; bias = bv1; out = v3;  doSM = false; loc = id - 256; }
  else if (id < 576) { A = f4p; Bt = Wk2B; bias = bk2; out = ks4; doSM = true;  loc = id - 512; }
  else               { A = f4b; Bt = Wv2B; bias = bv2; out = v4;  doSM = false; loc = id - 576; }
  const int nBase = (loc & 3) * 128, mBase = (loc >> 2) * 128;
  const int t = threadIdx.x, w = t >> 6, lane = t & 63;
  const int l15 = lane & 15, l4 = lane >> 4;
  const int wm = (w >> 1) * 64, wn = (w & 1) * 64;

  f32x4 acc[4][4];
#pragma unroll
  for (int i = 0; i < 4; i++)
#pragma unroll
    for (int j = 0; j < 4; j++) acc[i][j] = (f32x4){0.f, 0.f, 0.f, 0.f};

  gemm_core(A, Bt, 512, mBase, nBase, As, Bs, acc);

  const int N = 512;
  float bcol[4];
#pragma unroll
  for (int fn = 0; fn < 4; fn++) bcol[fn] = bias[nBase + wn + fn * 16 + l15];

  if (doSM) {
#pragma unroll
    for (int fm = 0; fm < 4; fm++) {
#pragma unroll
      for (int r = 0; r < 4; r++) {
        float x[4], m = -1e30f;
#pragma unroll
        for (int fn = 0; fn < 4; fn++) { x[fn] = acc[fm][fn][r] + bcol[fn]; m = fmaxf(m, x[fn]); }
        m = fmaxf(m, __shfl_xor(m, 1));
        m = fmaxf(m, __shfl_xor(m, 2));
        m = fmaxf(m, __shfl_xor(m, 4));
        m = fmaxf(m, __shfl_xor(m, 8));
        float s = 0.f;
#pragma unroll
        for (int fn = 0; fn < 4; fn++) { x[fn] = __expf(x[fn] - m); s += x[fn]; }
        s += __shfl_xor(s, 1);
        s += __shfl_xor(s, 2);
        s += __shfl_xor(s, 4);
        s += __shfl_xor(s, 8);
        float inv = 1.f / s;
        int row = mBase + wm + fm * 16 + l4 * 4 + r;
#pragma unroll
        for (int fn = 0; fn < 4; fn++)
          out[(size_t)row * N + nBase + wn + fn * 16 + l15] = f2bf(x[fn] * inv);
      }
    }
  } else {
#pragma unroll
    for (int fm = 0; fm < 4; fm++) {
#pragma unroll
      for (int r = 0; r < 4; r++) {
        int row = mBase + wm + fm * 16 + l4 * 4 + r;
#pragma unroll
        for (int fn = 0; fn < 4; fn++)
          out[(size_t)row * N + nBase + wn + fn * 16 + l15] =
              f2bf(acc[fm][fn][r] + bcol[fn]);
      }
    }
  }
}

// ---------------------------------------------------------------------------
// ctx standalone + prepB (fallback path, small ws only)
// ---------------------------------------------------------------------------
__global__ __launch_bounds__(256)
void ctx_kernel(const ushort_t* __restrict__ ks3, const ushort_t* __restrict__ v3,
                const ushort_t* __restrict__ ks4, const ushort_t* __restrict__ v4,
                float* __restrict__ ctxP) {
  __shared__ ushort_t sm[8704];
  ctx_block(ks3, v3, ks4, v4, ctxP, blockIdx.x, sm);
}

__global__ __launch_bounds__(256)
void prepB_kernel(const float* __restrict__ f2, const float* __restrict__ f2pe,
                  ushort_t* __restrict__ f2p) {
  const int base = blockIdx.x * 1024, t = threadIdx.x;
  const float4* A4 = reinterpret_cast<const float4*>(f2);
  const float4* P4 = reinterpret_cast<const float4*>(f2pe);
#pragma unroll
  for (int j = 0; j < 4; j++) {
    int i = base + j * 256 + t;
    float4 a = A4[i], p = P4[i];
    reinterpret_cast<ushort4*>(f2p)[i] = cvt4s(a, p);
  }
}

// ---------------------------------------------------------------------------
// G2: out_fp32 = E @ Mt(batch)^T + br.  grid 1024 = 256 m x 4 n, XCD swizzle.
// ---------------------------------------------------------------------------
__global__ __launch_bounds__(256, 4)
void gemm_g2(const ushort_t* __restrict__ E, const ushort_t* __restrict__ Mt,
             const float* __restrict__ bias, float* __restrict__ C) {
  __shared__ ushort_t As[8192], Bs[8192];
  const int bid = blockIdx.x;
  const int swz = (bid & 7) * 128 + (bid >> 3);
  const int tx = swz & 3, ty = swz >> 2;
  const int mBase = ty * 128, nBase = tx * 128;
  const ushort_t* Btb = Mt + (size_t)(ty >> 5) * 524288;
  const int t = threadIdx.x, w = t >> 6, lane = t & 63;
  const int l15 = lane & 15, l4 = lane >> 4;
  const int wm = (w >> 1) * 64, wn = (w & 1) * 64;

  f32x4 acc[4][4];
#pragma unroll
  for (int i = 0; i < 4; i++)
#pragma unroll
    for (int j = 0; j < 4; j++) acc[i][j] = (f32x4){0.f, 0.f, 0.f, 0.f};

  gemm_core(E, Btb, 1024, mBase, nBase, As, Bs, acc);

  const int N = 512;
  float bcol[4];
#pragma unroll
  for (int fn = 0; fn < 4; fn++) bcol[fn] = bias[nBase + wn + fn * 16 + l15];
#pragma unroll
  for (int fm = 0; fm < 4; fm++) {
#pragma unroll
    for (int r = 0; r < 4; r++) {
      int row = mBase + wm + fm * 16 + l4 * 4 + r;
#pragma unroll
      for (int fn = 0; fn < 4; fn++)
        C[(size_t)row * N + nBase + wn + fn * 16 + l15] = acc[fm][fn][r] + bcol[fn];
    }
  }
}

// ---------------------------------------------------------------------------
// Fold: Mt[b][j][c] = (sum_e ctx[branch,b,h,d,e]*Wr[j, branch*512+h*64+e]) / Z[b,c]
// branch-3 ctx = sum of 4 partial tiles; branch-4 single tile.
// ---------------------------------------------------------------------------
__global__ __launch_bounds__(256)
void fold_kernel(const float* __restrict__ ctxP, const float* __restrict__ Wr,
                 const float* __restrict__ Z, ushort_t* __restrict__ Mt) {
  __shared__ float ctxT[64][68];   // [e][d]
  __shared__ float wrT[64][68];    // [e][jl]
  __shared__ float zinv[64];
  int blk = blockIdx.x;
  int jc = blk & 7;
  int h = (blk >> 3) & 7;
  int branch = (blk >> 6) & 1;
  int b = blk >> 7;
  int t = threadIdx.x;
  int cbase = branch * 512 + h * 64;
  if (branch == 0) {
    const float* p = ctxP + (size_t)((b * 8 + h) * 4) * 4096;
#pragma unroll
    for (int i = 0; i < 16; i++) {
      int idx = i * 256 + t;
      int d = idx >> 6, e = idx & 63;
      int o = d * 64 + e;
      ctxT[e][d] = p[o] + p[4096 + o] + p[8192 + o] + p[12288 + o];
    }
  } else {
    const float* p = ctxP + 1048576 + (size_t)(b * 8 + h) * 4096;
#pragma unroll
    for (int i = 0; i < 16; i++) {
      int idx = i * 256 + t;
      int d = idx >> 6, e = idx & 63;
      ctxT[e][d] = p[d * 64 + e];
    }
  }
#pragma unroll
  for (int i = 0; i < 16; i++) {
    int idx = i * 256 + t;
    int jl = idx >> 6, e = idx & 63;
    wrT[e][jl] = Wr[(size_t)(jc * 64 + jl) * 1024 + cbase + e];
  }
  if (t < 64) zinv[t] = 1.0f / Z[b * 1024 + cbase + t];
  __syncthreads();
  int td = t & 15, tj = t >> 4;
  float acc[4][4] = {};   // [d_i][jj]
#pragma unroll 8
  for (int e = 0; e < 64; e++) {
    float4 cv = *reinterpret_cast<const float4*>(&ctxT[e][td * 4]);
    float4 wv = *reinterpret_cast<const float4*>(&wrT[e][tj * 4]);
    float ca[4] = {cv.x, cv.y, cv.z, cv.w};
    float wa[4] = {wv.x, wv.y, wv.z, wv.w};
#pragma unroll
    for (int i = 0; i < 4; i++)
#pragma unroll
      for (int jj = 0; jj < 4; jj++) acc[i][jj] += ca[i] * wa[jj];
  }
  float zi[4] = {zinv[td * 4], zinv[td * 4 + 1], zinv[td * 4 + 2], zinv[td * 4 + 3]};
#pragma unroll
  for (int jj = 0; jj < 4; jj++) {
    ushort4 u;
    u.x = f2bf(acc[0][jj] * zi[0]);
    u.y = f2bf(acc[1][jj] * zi[1]);
    u.z = f2bf(acc[2][jj] * zi[2]);
    u.w = f2bf(acc[3][jj] * zi[3]);
    *reinterpret_cast<ushort4*>(
        &Mt[(size_t)(b * 512 + jc * 64 + tj * 4 + jj) * 1024 + cbase + td * 4]) = u;
  }
}

// ---------------------------------------------------------------------------
extern "C" void kernel_launch(void* const* d_in, const int* in_sizes, int n_in,
                              void* d_out, int out_size, void* d_ws, size_t ws_size,
                              hipStream_t stream) {
  const float* f2 = (const float*)d_in[0];
  const float* f3 = (const float*)d_in[1];
  const float* f4 = (const float*)d_in[2];
  const float* f2pe = (const float*)d_in[3];
  const float* f3pe = (const float*)d_in[4];
  const float* f4pe = (const float*)d_in[5];
  const float* Wq1 = (const float*)d_in[6];
  const float* bq1 = (const float*)d_in[7];
  const float* Wk1 = (const float*)d_in[8];
  const float* bk1 = (const float*)d_in[9];
  const float* Wv1 = (const float*)d_in[10];
  const float* bv1 = (const float*)d_in[11];
  const float* Wq2 = (const float*)d_in[12];
  const float* bq2 = (const float*)d_in[13];
  const float* Wk2 = (const float*)d_in[14];
  const float* bk2 = (const float*)d_in[15];
  const float* Wv2 = (const float*)d_in[16];
  const float* bv2 = (const float*)d_in[17];
  const float* Wr = (const float*)d_in[18];
  const float* br = (const float*)d_in[19];

  char* ws = (char*)d_ws;
  // Region 0: E bf16 [32768,1024]
  ushort_t* E = (ushort_t*)(ws + 0);                       // 67,108,864 B
  // Region 1 (33.5 MB): kv inputs; small-ws path reuses it for f2p after kvq
  char* R1 = ws + 67108864;
  ushort_t* f3p = (ushort_t*)R1;                           // 8,388,608
  ushort_t* f3b = (ushort_t*)(R1 + 8388608);               // 8,388,608
  ushort_t* f4p = (ushort_t*)(R1 + 16777216);              // 2,097,152
  ushort_t* f4b = (ushort_t*)(R1 + 18874368);              // 2,097,152
  // Region 2: kv GEMM outputs (softmaxed k + v, bf16)
  char* R2 = ws + 100663296;
  ushort_t* ks3 = (ushort_t*)R2;
  ushort_t* v3b = (ushort_t*)(R2 + 8388608);
  ushort_t* ks4 = (ushort_t*)(R2 + 16777216);
  ushort_t* v4b = (ushort_t*)(R2 + 18874368);
  // Region 3: weights bf16, Mt, Z, bqc, ctx partials (5 MB)
  char* R3 = ws + 121634816;
  ushort_t* WqB = (ushort_t*)R3;                           // 1,048,576
  ushort_t* Wk1B = (ushort_t*)(R3 + 1048576);
  ushort_t* Wv1B = (ushort_t*)(R3 + 1572864);
  ushort_t* Wk2B = (ushort_t*)(R3 + 2097152);
  ushort_t* Wv2B = (ushort_t*)(R3 + 2621440);
  ushort_t* Mt = (ushort_t*)(R3 + 3145728);                // 8,388,608
  float* Z = (float*)(R3 + 11534336);                      // 32,768
  float* bqc = (float*)(R3 + 11567104);                    // 4,096
  float* ctxP = (float*)(R3 + 11571200);                   // 5,242,880
  // Region 4 (big-ws only): dedicated f2p, disjoint from all live buffers
  const bool bigWS = ws_size >= (size_t)176160768;         // needs 168 MiB
  ushort_t* f2p = bigWS ? (ushort_t*)(ws + 142606336) : (ushort_t*)R1;

  // ---- prepA: kv inputs, weights->bf16, bqc, Z=0 ----
  prepA_kernel<<<3329, 256, 0, stream>>>(f3, f3pe, f4, f4pe,
                                         Wq1, Wq2, Wk1, Wv1, Wk2, Wv2, bq1, bq2,
                                         f3p, f3b, f4p, f4b,
                                         WqB, Wk1B, Wv1B, Wk2B, Wv2B, bqc, Z);

  if (bigWS) {
    // kv GEMMs (640, first) then f2p stream (2048) — sequential, measured best
    kv_quad<<<2688, 256, 0, stream>>>(f3p, f3b, f4p, f4b,
                                      Wk1B, Wv1B, Wk2B, Wv2B,
                                      bk1, bv1, bk2, bv2,
                                      ks3, v3b, ks4, v4b, f2, f2pe, f2p);
    // G1 GEMM (2048) + LEADING ctx (320) — ctx hides in the dispatch ramp
    gemm_g1<<<2368, 256, 0, stream>>>(f2p, WqB, bqc, E, Z,
                                      ks3, v3b, ks4, v4b, ctxP, 320);
  } else {
    kv_quad<<<640, 256, 0, stream>>>(f3p, f3b, f4p, f4b,
                                     Wk1B, Wv1B, Wk2B, Wv2B,
                                     bk1, bv1, bk2, bv2,
                                     ks3, v3b, ks4, v4b, f2, f2pe, f2p);
    prepB_kernel<<<4096, 256, 0, stream>>>(f2, f2pe, f2p);
    ctx_kernel<<<320, 256, 0, stream>>>(ks3, v3b, ks4, v4b, ctxP);
    gemm_g1<<<2048, 256, 0, stream>>>(f2p, WqB, bqc, E, Z,
                                      ks3, v3b, ks4, v4b, ctxP, 0);
  }

  // ---- fold ctx partials, Wr, 1/Z into per-batch Mt[b][j][c] ----
  fold_kernel<<<1024, 256, 0, stream>>>(ctxP, Wr, Z, Mt);

  // ---- G2: out = E @ Mt^T + br (E L3-hot from G1) ----
  gemm_g2<<<1024, 256, 0, stream>>>(E, Mt, br, (float*)d_out);
}